// Round 2
// baseline (151.586 us; speedup 1.0000x reference)
//
#include <hip/hip_runtime.h>
#include <hip/hip_bf16.h>
#include <math.h>

// N_AGENTS=16, RNN_H=64, N_HEADS=4, GAT_D=32, EMB=32, SDIM=128, B=4096 rows

typedef __attribute__((ext_vector_type(8))) short short8;
typedef __attribute__((ext_vector_type(8))) unsigned short ushort8;
typedef __attribute__((ext_vector_type(4))) float float4v;
typedef __attribute__((ext_vector_type(4))) _Float16 half4v;

static __device__ inline unsigned short f2bf(float f) {
    unsigned int x;
    __builtin_memcpy(&x, &f, 4);
    unsigned int r = x + 0x7fffu + ((x >> 16) & 1u);   // RNE
    return (unsigned short)(r >> 16);
}

// packed f32x2 -> bf16x2 (v_cvt_pk_bf16_f32, RNE)
static __device__ inline unsigned int cvtpk(float lo, float hi) {
    __hip_bfloat162 h = __float22bfloat162_rn(make_float2(lo, hi));
    unsigned int u;
    __builtin_memcpy(&u, &h, 4);
    return u;
}

static __device__ inline short8 pack8(float4 f0, float4 f1) {
    unsigned int u[4] = {cvtpk(f0.x, f0.y), cvtpk(f0.z, f0.w),
                         cvtpk(f1.x, f1.y), cvtpk(f1.z, f1.w)};
    short8 s;
    __builtin_memcpy(&s, u, 16);
    return s;
}

// ---------------------------------------------------------------------------
// K0: prep + batched small GEMVs.
//  blocks 0..255   : w1s_W -> w1sTf, FRAG-MAJOR bf16
//  block 256       : W_gat -> WgTf frag-major (9 tiles incl. fused attention
//                    projections as tile 8)
//  blocks 257..320 : MFMA GEMVs -> b1v, wfv, out = v (bf16 LDS stage)
// ---------------------------------------------------------------------------
__global__ __launch_bounds__(256) void k0_prep(
    const float* __restrict__ w1s_W,     // [129][4096]
    const float* __restrict__ W_gat,     // [64][128]
    const float* __restrict__ att_a,     // [4][64]
    const float* __restrict__ states,    // [4096][128]
    const float* __restrict__ b1_W, const float* __restrict__ b1_b,
    const float* __restrict__ wf_W, const float* __restrict__ wf_b,
    const float* __restrict__ V1_W, const float* __restrict__ V1_b,
    const float* __restrict__ V2_W, const float* __restrict__ V2_b,
    unsigned short* __restrict__ w1sTf,  // [256 tiles][2048] bf16 frag-major
    unsigned short* __restrict__ WgTf,   // [9 tiles][1024] bf16 frag-major
    float* __restrict__ b1v, float* __restrict__ wfv,
    float* __restrict__ out)             // seeded with v
{
    __shared__ __align__(16) char SMEM[26112];
    const int tid = threadIdx.x, bx = blockIdx.x;

    if (bx < 256) {
        unsigned short* T = (unsigned short*)SMEM;    // [16 cols][136]
        const int c0 = bx * 16;
        const int cc = tid & 15, kr = tid >> 4;
        #pragma unroll
        for (int t = 0; t < 8; ++t) {
            int k = t * 16 + kr;
            T[cc * 136 + k] = f2bf(w1s_W[(size_t)k * 4096 + c0 + cc]);
        }
        __syncthreads();
        const int ks = tid >> 6, q = (tid >> 4) & 3, mm = tid & 15;
        *(ushort8*)&w1sTf[(size_t)bx * 2048 + tid * 8] =
            *(const ushort8*)&T[mm * 136 + ks * 32 + q * 8];
    } else if (bx == 256) {
        unsigned short* T = (unsigned short*)SMEM;    // [128 cols][72]
        #pragma unroll
        for (int t = 0; t < 32; ++t) {
            int i = t * 256 + tid;
            int k = i >> 7, c = i & 127;
            T[c * 72 + k] = f2bf(W_gat[k * 128 + c]);
        }
        __syncthreads();
        #pragma unroll
        for (int t = 0; t < 4; ++t) {
            int i = t * 256 + tid;            // < 1024 ushort8 groups
            int nt = i >> 7, w = i & 127;
            int kh = w >> 6, q = (w >> 4) & 3, mm = w & 15;
            *(ushort8*)&WgTf[nt * 1024 + w * 8] =
                *(const ushort8*)&T[(nt * 16 + mm) * 72 + kh * 32 + q * 8];
        }
        // tile 8: fused attention projections (m = h: src, m = 4+h: dst)
        {
            const int k = tid >> 2, h = tid & 3;
            float ss = 0.f, dd = 0.f;
            #pragma unroll
            for (int d = 0; d < 32; ++d) {
                float wv = W_gat[k * 128 + h * 32 + d];
                ss = fmaf(wv, att_a[h * 64 + d], ss);
                dd = fmaf(wv, att_a[h * 64 + 32 + d], dd);
            }
            const int base = 8192 + (k >> 5) * 512 + ((k >> 3) & 3) * 128 + (k & 7);
            WgTf[base + h * 8]       = f2bf(ss);
            WgTf[base + (4 + h) * 8] = f2bf(dd);
        }
        #pragma unroll
        for (int t = 0; t < 2; ++t) {         // zero cols m = 8..15
            int i = t * 256 + tid;            // < 512
            int kh = i >> 8, q = (i >> 6) & 3, mm = 8 + ((i >> 3) & 7), j = i & 7;
            WgTf[8192 + kh * 512 + q * 128 + mm * 8 + j] = 0;
        }
    } else {
        // ---- MFMA GEMV block: 64 rows, 4 waves x 16 rows ----
        // WLu: bf16 [3][128][34] (stride 34 -> 2-way max bank alias = free)
        unsigned short* WLu = (unsigned short*)SMEM;  // 26112 B
        for (int i = tid; i < 12288; i += 256) {
            float v = (i < 4096) ? b1_W[i] : (i < 8192 ? wf_W[i - 4096] : V1_W[i - 8192]);
            int set = i >> 12, k = (i >> 5) & 127, e = i & 31;
            WLu[set * 4352 + k * 34 + e] = f2bf(v);
        }
        __syncthreads();

        const int wave = tid >> 6, lane = tid & 63, mm = lane & 15, q = lane >> 4;
        const int b0w = (bx - 257) * 64 + wave * 16;

        short8 a[4];
        #pragma unroll
        for (int ks = 0; ks < 4; ++ks) {
            const float* sp = states + (size_t)(b0w + mm) * 128 + ks * 32 + q * 8;
            a[ks] = pack8(*(const float4*)sp, *(const float4*)(sp + 4));
        }
        float4v accT[6];
        #pragma unroll
        for (int nt = 0; nt < 6; ++nt) accT[nt] = (float4v){0.f, 0.f, 0.f, 0.f};
        #pragma unroll
        for (int nt = 0; nt < 6; ++nt) {
            const int set = nt >> 1, e = (nt & 1) * 16 + mm;
            #pragma unroll
            for (int ks = 0; ks < 4; ++ks) {
                ushort8 bfu;
                #pragma unroll
                for (int j = 0; j < 8; ++j)
                    bfu[j] = WLu[set * 4352 + (ks * 32 + q * 8 + j) * 34 + e];
                short8 bf;
                __builtin_memcpy(&bf, &bfu, 16);
                accT[nt] = __builtin_amdgcn_mfma_f32_16x16x32_bf16(a[ks], bf, accT[nt], 0, 0, 0);
            }
        }
        float vsum[4] = {0.f, 0.f, 0.f, 0.f};
        #pragma unroll
        for (int p = 0; p < 2; ++p) {
            const int e = p * 16 + mm;
            const float bb1 = b1_b[e], bwf = wf_b[e], bv1 = V1_b[e], v2 = V2_W[e];
            #pragma unroll
            for (int reg = 0; reg < 4; ++reg) {
                const int row = b0w + q * 4 + reg;
                b1v[(size_t)row * 32 + e] = accT[p][reg] + bb1;
                wfv[(size_t)row * 32 + e] = fabsf(accT[2 + p][reg] + bwf);
                vsum[reg] += fmaxf(accT[4 + p][reg] + bv1, 0.f) * v2;
            }
        }
        #pragma unroll
        for (int reg = 0; reg < 4; ++reg) {
            vsum[reg] += __shfl_xor(vsum[reg], 1);
            vsum[reg] += __shfl_xor(vsum[reg], 2);
            vsum[reg] += __shfl_xor(vsum[reg], 4);
            vsum[reg] += __shfl_xor(vsum[reg], 8);
        }
        if (mm == 0) {
            #pragma unroll
            for (int reg = 0; reg < 4; ++reg)
                out[b0w + q * 4 + reg] = vsum[reg] + V2_b[0];
        }
    }
}

// ---------------------------------------------------------------------------
// K1: GAT, 1 wave = 1 batch row. g stored in d'-interleaved layout:
// d' = 2*(d&15) + (d>>4)  (pairs (d, d+16) adjacent -> one 16B store per head;
// k2 phase-2 contracts both operands in the same d' permutation).
// ---------------------------------------------------------------------------
__global__ __launch_bounds__(256) void k1_gat(
    const float* __restrict__ hidden_states,  // [4096*16][64] fp32
    const unsigned short* __restrict__ WgTf,  // [9][1024] bf16 frag-major
    unsigned short* __restrict__ g_bf)        // [B][4][16][32] bf16 (d' order)
{
    const int wave = threadIdx.x >> 6;
    const int b = blockIdx.x * 4 + wave;
    const int lane = threadIdx.x & 63, m = lane & 15, quad = lane >> 4;
    __shared__ __align__(16) float sc[4 * 320];   // per-wave scratch, 5KB
    float* scr = &sc[wave * 320];

    // ---- MFMA1: 8 hp tiles + proj tile ----
    const float* hrow = hidden_states + ((size_t)b * 16 + m) * 64;
    float4 f0 = *(const float4*)(hrow + quad * 8);
    float4 f1 = *(const float4*)(hrow + quad * 8 + 4);
    short8 a0 = pack8(f0, f1);
    f0 = *(const float4*)(hrow + 32 + quad * 8);
    f1 = *(const float4*)(hrow + 32 + quad * 8 + 4);
    short8 a1 = pack8(f0, f1);

    float4v hpt[9];
    #pragma unroll
    for (int nt = 0; nt < 9; ++nt) {
        short8 bf0 = *(const short8*)&WgTf[nt * 1024 + lane * 8];
        short8 bf1 = *(const short8*)&WgTf[nt * 1024 + 512 + lane * 8];
        float4v z = (float4v){0.f, 0.f, 0.f, 0.f};
        z = __builtin_amdgcn_mfma_f32_16x16x32_bf16(a0, bf0, z, 0, 0, 0);
        z = __builtin_amdgcn_mfma_f32_16x16x32_bf16(a1, bf1, z, 0, 0, 0);
        hpt[nt] = z;
    }

    // stash proj tile transposed: scr[col*20 + row]
    {
        float4 pr = {hpt[8][0], hpt[8][1], hpt[8][2], hpt[8][3]};
        *(float4*)&scr[m * 20 + quad * 4] = pr;
    }

    // ---- per head: softmax + MFMA2 ----
    #pragma unroll
    for (int h = 0; h < 4; ++h) {
        const float src_m = scr[h * 20 + m];                        // src[i=m]
        float4 pdv = *(const float4*)&scr[(4 + h) * 20 + quad * 4]; // dst[j]
        float pd[4] = {pdv.x, pdv.y, pdv.z, pdv.w};

        float e_[4];
        #pragma unroll
        for (int jj = 0; jj < 4; ++jj) {
            float x = src_m + pd[jj];
            e_[jj] = fmaxf(x, 0.2f * x);       // leaky_relu(0.2)
        }
        float mx = fmaxf(fmaxf(e_[0], e_[1]), fmaxf(e_[2], e_[3]));
        mx = fmaxf(mx, __shfl_xor(mx, 16));
        mx = fmaxf(mx, __shfl_xor(mx, 32));
        float p_[4], ssum = 0.f;
        #pragma unroll
        for (int jj = 0; jj < 4; ++jj) { p_[jj] = __expf(e_[jj] - mx); ssum += p_[jj]; }
        ssum += __shfl_xor(ssum, 16);
        ssum += __shfl_xor(ssum, 32);
        const float inv = __builtin_amdgcn_rcpf(ssum);

        half4v bfrag;   // B[k=j=quad*4+jj][n=i=m] = attn[i][j]
        #pragma unroll
        for (int jj = 0; jj < 4; ++jj) bfrag[jj] = (_Float16)(p_[jj] * inv);

        float4v zp[2];
        #pragma unroll
        for (int p = 0; p < 2; ++p) {
            float4v ct = hpt[2 * h + p];       // A[m=d'][k=j=quad*4+t]
            half4v afrag;
            #pragma unroll
            for (int t = 0; t < 4; ++t) afrag[t] = (_Float16)ct[t];
            float4v z = (float4v){0.f, 0.f, 0.f, 0.f};
            zp[p] = __builtin_amdgcn_mfma_f32_16x16x16f16(afrag, bfrag, z, 0, 0, 0);
        }
        // elu + packed d'-interleaved store: value (p,t) -> d' = quad*8+2t+p
        unsigned int w[4];
        #pragma unroll
        for (int t = 0; t < 4; ++t) {
            float x0 = zp[0][t];
            x0 = (x0 > 0.f) ? x0 : (__expf(x0) - 1.f);
            float x1 = zp[1][t];
            x1 = (x1 > 0.f) ? x1 : (__expf(x1) - 1.f);
            w[t] = cvtpk(x0, x1);
        }
        short8 o8;
        __builtin_memcpy(&o8, w, 16);
        *(short8*)&g_bf[((size_t)b * 4 + h) * 512 + m * 32 + quad * 8] = o8;
    }
}

// ---------------------------------------------------------------------------
// K2_mix v3: occupancy-first fused GEMM + contraction + epilogue.
// Grid (256, 8): block = (16-row strip, e-group of 4 e's), 2048 blocks,
// LDS 10.5KB -> ~8 blocks/CU resident (was 4). Per h: phase1 = 2 tiles/wave
// (8 MFMA), d'-interleaved bf16 LDS tile written as 4 packed b32 per wave
// (was 64 scalar b16); ONE barrier; phase2 direct-bf16 A-frag MFMA vs g.
// ---------------------------------------------------------------------------
__global__ __launch_bounds__(256) void k2_mix(
    const float* __restrict__ states,           // [4096][128] fp32
    const unsigned short* __restrict__ w1sTf,   // [256 tiles][2048] frag-major
    const unsigned short* __restrict__ g_bf,    // [4096][4][16][32] (d' order)
    const float* __restrict__ agent_qs,         // [4096][16]
    const float* __restrict__ uncertainty,      // [4096]
    const float* __restrict__ w1s_W,            // row 128 used
    const float* __restrict__ w1s_b,
    const float* __restrict__ b1v, const float* __restrict__ wfv,
    float* __restrict__ out)                    // pre-seeded with v
{
    const int r0 = blockIdx.x * 16;
    const int eg = blockIdx.y;                  // 0..7, 4 e's per block
    const int wave = threadIdx.x >> 6;          // = e_local owned in phase1
    const int lane = threadIdx.x & 63, m = lane & 15, quad = lane >> 4;
    // dbuf bf16 tile: [2][16 rows][4 el x 40 + 8 pad], row stride 168 ushorts
    __shared__ __align__(16) unsigned short Wt[2][16 * 168];   // 10.5KB

    // A-frags: one m-tile, rows r0..r0+15
    short8 a[4];
    #pragma unroll
    for (int ks = 0; ks < 4; ++ks) {
        const float* sp = states + (size_t)(r0 + m) * 128 + ks * 32 + quad * 8;
        a[ks] = pack8(*(const float4*)sp, *(const float4*)(sp + 4));
    }
    float us[4];
    #pragma unroll
    for (int reg = 0; reg < 4; ++reg)
        us[reg] = uncertainty[r0 + quad * 4 + reg];
    float qs_r[4];
    #pragma unroll
    for (int rr = 0; rr < 4; ++rr)
        qs_r[rr] = agent_qs[(r0 + wave * 4 + rr) * 16 + m];

    const float* w128 = w1s_W + (size_t)128 * 4096;
    float Sacc[4][4] = {};

    #pragma unroll
    for (int h = 0; h < 4; ++h) {
        unsigned short* buf = &Wt[h & 1][0];

        // ---- Phase 1: wave owns e_local = wave; t covers d = t*16+m ----
        float4v acc0, acc1;
        #pragma unroll
        for (int t = 0; t < 2; ++t) {
            const int ctl = wave * 2 + t;                // local col-tile
            const int ct = h * 64 + eg * 8 + ctl;        // global col-tile
            const int c_loc = ctl * 16 + m;              // in [0,128)
            const int cg = h * 1024 + eg * 128 + c_loc;
            const float wfix = w128[cg], bias = w1s_b[cg];
            float4v z = (float4v){0.f, 0.f, 0.f, 0.f};
            #pragma unroll
            for (int ks = 0; ks < 4; ++ks) {
                short8 bfr = *(const short8*)&w1sTf[(size_t)ct * 2048 + ks * 512 + lane * 8];
                z = __builtin_amdgcn_mfma_f32_16x16x32_bf16(a[ks], bfr, z, 0, 0, 0);
            }
            #pragma unroll
            for (int reg = 0; reg < 4; ++reg)
                z[reg] = z[reg] + us[reg] * wfix + bias;
            if (t == 0) acc0 = z; else acc1 = z;
        }
        // paired d'-interleaved writes: (t0,t1) -> d' = 2m, 2m+1 (one b32/row)
        #pragma unroll
        for (int reg = 0; reg < 4; ++reg) {
            const int row = quad * 4 + reg;
            unsigned int pair = cvtpk(acc0[reg], acc1[reg]);
            *(unsigned int*)&buf[row * 168 + wave * 40 + 2 * m] = pair;
        }

        // prefetch g frags (global, independent of LDS) before the barrier
        short8 gf[4];
        #pragma unroll
        for (int rr = 0; rr < 4; ++rr)
            gf[rr] = *(const short8*)&g_bf[((size_t)(r0 + wave * 4 + rr) * 4 + h) * 512 + m * 32 + quad * 8];

        __syncthreads();

        // ---- Phase 2: wave w -> rows w*4..+4; Sacc += |z| ----
        #pragma unroll
        for (int rr = 0; rr < 4; ++rr) {
            const int r = wave * 4 + rr;
            short8 af = *(const short8*)&buf[r * 168 + (m & 3) * 40 + quad * 8];
            float4v z = (float4v){0.f, 0.f, 0.f, 0.f};
            z = __builtin_amdgcn_mfma_f32_16x16x32_bf16(af, gf[rr], z, 0, 0, 0);
            #pragma unroll
            for (int reg = 0; reg < 4; ++reg)
                Sacc[rr][reg] += fabsf(z[reg]);
        }
        // no second barrier: next h writes the OTHER buffer; reuse of this
        // buffer (h+2) is separated by the h+1 barrier.
    }

    // ---- Epilogue: qs, n-reduce, b1+elu+wf, e-sum, atomic into out ----
    // Phase-2 z rows: e_local = (quad*4+reg)&3 = reg (all quads duplicate).
    #pragma unroll
    for (int rr = 0; rr < 4; ++rr) {
        const int r = r0 + wave * 4 + rr;
        float sn[4];
        #pragma unroll
        for (int reg = 0; reg < 4; ++reg) sn[reg] = Sacc[rr][reg] * qs_r[rr];
        #pragma unroll
        for (int mask = 1; mask <= 8; mask <<= 1) {
            #pragma unroll
            for (int reg = 0; reg < 4; ++reg) sn[reg] += __shfl_xor(sn[reg], mask);
        }
        float4 b4 = *(const float4*)&b1v[(size_t)r * 32 + eg * 4];
        float4 w4 = *(const float4*)&wfv[(size_t)r * 32 + eg * 4];
        float bq[4] = {b4.x, b4.y, b4.z, b4.w};
        float wq[4] = {w4.x, w4.y, w4.z, w4.w};
        float local = 0.f;
        #pragma unroll
        for (int reg = 0; reg < 4; ++reg) {
            float hid = 0.25f * sn[reg] + bq[reg];
            hid = (hid > 0.f) ? hid : expm1f(hid);
            local = fmaf(hid, wq[reg], local);
        }
        if (lane == 0) atomicAdd(&out[r], local);
    }
}

// ---------------------------------------------------------------------------
extern "C" void kernel_launch(void* const* d_in, const int* in_sizes, int n_in,
                              void* d_out, int out_size, void* d_ws, size_t ws_size,
                              hipStream_t stream)
{
    const float* agent_qs      = (const float*)d_in[0];
    const float* states        = (const float*)d_in[1];
    const float* hidden_states = (const float*)d_in[2];
    const float* uncertainty   = (const float*)d_in[3];
    const float* W_gat         = (const float*)d_in[4];
    const float* att_a         = (const float*)d_in[5];
    const float* w1s_W         = (const float*)d_in[6];
    const float* w1s_b         = (const float*)d_in[7];
    const float* b1_W          = (const float*)d_in[8];
    const float* b1_b          = (const float*)d_in[9];
    const float* wf_W          = (const float*)d_in[10];
    const float* wf_b          = (const float*)d_in[11];
    const float* V1_W          = (const float*)d_in[12];
    const float* V1_b          = (const float*)d_in[13];
    const float* V2_W          = (const float*)d_in[14];
    const float* V2_b          = (const float*)d_in[15];

    char* w = (char*)d_ws;
    unsigned short* w1sTf   = (unsigned short*)w;  w += (size_t)524288 * 2;
    unsigned short* WgTf    = (unsigned short*)w;  w += (size_t)9216 * 2;
    unsigned short* g_bf    = (unsigned short*)w;  w += (size_t)8388608 * 2;
    float* b1v              = (float*)w;           w += (size_t)131072 * 4;
    float* wfv              = (float*)w;           w += (size_t)131072 * 4;
    float* out              = (float*)d_out;

    k0_prep<<<321, 256, 0, stream>>>(w1s_W, W_gat, att_a, states,
                                     b1_W, b1_b, wf_W, wf_b, V1_W, V1_b,
                                     V2_W, V2_b, w1sTf, WgTf, b1v, wfv, out);

    k1_gat<<<1024, 256, 0, stream>>>(hidden_states, WgTf, g_bf);

    dim3 gmix(256, 8);
    k2_mix<<<gmix, 256, 0, stream>>>(states, w1sTf, g_bf, agent_qs, uncertainty,
                                     w1s_W, w1s_b, b1v, wfv, out);
}

// Round 3
// 130.281 us; speedup vs baseline: 1.1635x; 1.1635x over previous
//
#include <hip/hip_runtime.h>
#include <hip/hip_bf16.h>
#include <math.h>

// N_AGENTS=16, RNN_H=64, N_HEADS=4, GAT_D=32, EMB=32, SDIM=128, B=4096 rows

typedef __attribute__((ext_vector_type(8))) short short8;
typedef __attribute__((ext_vector_type(8))) unsigned short ushort8;
typedef __attribute__((ext_vector_type(4))) float float4v;
typedef __attribute__((ext_vector_type(4))) _Float16 half4v;

static __device__ inline unsigned short f2bf(float f) {
    unsigned int x;
    __builtin_memcpy(&x, &f, 4);
    unsigned int r = x + 0x7fffu + ((x >> 16) & 1u);   // RNE
    return (unsigned short)(r >> 16);
}

// packed f32x2 -> bf16x2 (v_cvt_pk_bf16_f32, RNE)
static __device__ inline unsigned int cvtpk(float lo, float hi) {
    __hip_bfloat162 h = __float22bfloat162_rn(make_float2(lo, hi));
    unsigned int u;
    __builtin_memcpy(&u, &h, 4);
    return u;
}

static __device__ inline short8 pack8(float4 f0, float4 f1) {
    unsigned int u[4] = {cvtpk(f0.x, f0.y), cvtpk(f0.z, f0.w),
                         cvtpk(f1.x, f1.y), cvtpk(f1.z, f1.w)};
    short8 s;
    __builtin_memcpy(&s, u, 16);
    return s;
}

// ---------------------------------------------------------------------------
// K0: prep + batched small GEMVs.
//  blocks 0..255   : w1s_W -> w1sTf, FRAG-MAJOR bf16
//  block 256       : W_gat -> WgTf frag-major (9 tiles incl. fused attention
//                    projections as tile 8)
//  blocks 257..320 : MFMA GEMVs -> b1v, wfv, out = v; also stores states
//                    bf16-packed frags -> Sbf [4096][128] for k2a.
// ---------------------------------------------------------------------------
__global__ __launch_bounds__(256) void k0_prep(
    const float* __restrict__ w1s_W,     // [129][4096]
    const float* __restrict__ W_gat,     // [64][128]
    const float* __restrict__ att_a,     // [4][64]
    const float* __restrict__ states,    // [4096][128]
    const float* __restrict__ b1_W, const float* __restrict__ b1_b,
    const float* __restrict__ wf_W, const float* __restrict__ wf_b,
    const float* __restrict__ V1_W, const float* __restrict__ V1_b,
    const float* __restrict__ V2_W, const float* __restrict__ V2_b,
    unsigned short* __restrict__ w1sTf,  // [256 tiles][2048] bf16 frag-major
    unsigned short* __restrict__ WgTf,   // [9 tiles][1024] bf16 frag-major
    unsigned short* __restrict__ Sbf,    // [4096][128] bf16 (frag octets)
    float* __restrict__ b1v, float* __restrict__ wfv,
    float* __restrict__ out)             // seeded with v
{
    __shared__ __align__(16) char SMEM[26112];
    const int tid = threadIdx.x, bx = blockIdx.x;

    if (bx < 256) {
        unsigned short* T = (unsigned short*)SMEM;    // [16 cols][136]
        const int c0 = bx * 16;
        const int cc = tid & 15, kr = tid >> 4;
        #pragma unroll
        for (int t = 0; t < 8; ++t) {
            int k = t * 16 + kr;
            T[cc * 136 + k] = f2bf(w1s_W[(size_t)k * 4096 + c0 + cc]);
        }
        __syncthreads();
        const int ks = tid >> 6, q = (tid >> 4) & 3, mm = tid & 15;
        *(ushort8*)&w1sTf[(size_t)bx * 2048 + tid * 8] =
            *(const ushort8*)&T[mm * 136 + ks * 32 + q * 8];
    } else if (bx == 256) {
        unsigned short* T = (unsigned short*)SMEM;    // [128 cols][72]
        #pragma unroll
        for (int t = 0; t < 32; ++t) {
            int i = t * 256 + tid;
            int k = i >> 7, c = i & 127;
            T[c * 72 + k] = f2bf(W_gat[k * 128 + c]);
        }
        __syncthreads();
        #pragma unroll
        for (int t = 0; t < 4; ++t) {
            int i = t * 256 + tid;            // < 1024 ushort8 groups
            int nt = i >> 7, w = i & 127;
            int kh = w >> 6, q = (w >> 4) & 3, mm = w & 15;
            *(ushort8*)&WgTf[nt * 1024 + w * 8] =
                *(const ushort8*)&T[(nt * 16 + mm) * 72 + kh * 32 + q * 8];
        }
        // tile 8: fused attention projections (m = h: src, m = 4+h: dst)
        {
            const int k = tid >> 2, h = tid & 3;
            float ss = 0.f, dd = 0.f;
            #pragma unroll
            for (int d = 0; d < 32; ++d) {
                float wv = W_gat[k * 128 + h * 32 + d];
                ss = fmaf(wv, att_a[h * 64 + d], ss);
                dd = fmaf(wv, att_a[h * 64 + 32 + d], dd);
            }
            const int base = 8192 + (k >> 5) * 512 + ((k >> 3) & 3) * 128 + (k & 7);
            WgTf[base + h * 8]       = f2bf(ss);
            WgTf[base + (4 + h) * 8] = f2bf(dd);
        }
        #pragma unroll
        for (int t = 0; t < 2; ++t) {         // zero cols m = 8..15
            int i = t * 256 + tid;            // < 512
            int kh = i >> 8, q = (i >> 6) & 3, mm = 8 + ((i >> 3) & 7), j = i & 7;
            WgTf[8192 + kh * 512 + q * 128 + mm * 8 + j] = 0;
        }
    } else {
        // ---- MFMA GEMV block: 64 rows, 4 waves x 16 rows ----
        // WLu: bf16 [3][128][34] (stride 34 -> 2-way max bank alias = free)
        unsigned short* WLu = (unsigned short*)SMEM;  // 26112 B
        for (int i = tid; i < 12288; i += 256) {
            float v = (i < 4096) ? b1_W[i] : (i < 8192 ? wf_W[i - 4096] : V1_W[i - 8192]);
            int set = i >> 12, k = (i >> 5) & 127, e = i & 31;
            WLu[set * 4352 + k * 34 + e] = f2bf(v);
        }
        __syncthreads();

        const int wave = tid >> 6, lane = tid & 63, mm = lane & 15, q = lane >> 4;
        const int b0w = (bx - 257) * 64 + wave * 16;

        short8 a[4];
        #pragma unroll
        for (int ks = 0; ks < 4; ++ks) {
            const float* sp = states + (size_t)(b0w + mm) * 128 + ks * 32 + q * 8;
            a[ks] = pack8(*(const float4*)sp, *(const float4*)(sp + 4));
        }
        // export packed states frags for k2a
        #pragma unroll
        for (int ks = 0; ks < 4; ++ks)
            *(short8*)&Sbf[(size_t)(b0w + mm) * 128 + ks * 32 + q * 8] = a[ks];

        float4v accT[6];
        #pragma unroll
        for (int nt = 0; nt < 6; ++nt) accT[nt] = (float4v){0.f, 0.f, 0.f, 0.f};
        #pragma unroll
        for (int nt = 0; nt < 6; ++nt) {
            const int set = nt >> 1, e = (nt & 1) * 16 + mm;
            #pragma unroll
            for (int ks = 0; ks < 4; ++ks) {
                ushort8 bfu;
                #pragma unroll
                for (int j = 0; j < 8; ++j)
                    bfu[j] = WLu[set * 4352 + (ks * 32 + q * 8 + j) * 34 + e];
                short8 bf;
                __builtin_memcpy(&bf, &bfu, 16);
                accT[nt] = __builtin_amdgcn_mfma_f32_16x16x32_bf16(a[ks], bf, accT[nt], 0, 0, 0);
            }
        }
        float vsum[4] = {0.f, 0.f, 0.f, 0.f};
        #pragma unroll
        for (int p = 0; p < 2; ++p) {
            const int e = p * 16 + mm;
            const float bb1 = b1_b[e], bwf = wf_b[e], bv1 = V1_b[e], v2 = V2_W[e];
            #pragma unroll
            for (int reg = 0; reg < 4; ++reg) {
                const int row = b0w + q * 4 + reg;
                b1v[(size_t)row * 32 + e] = accT[p][reg] + bb1;
                wfv[(size_t)row * 32 + e] = fabsf(accT[2 + p][reg] + bwf);
                vsum[reg] += fmaxf(accT[4 + p][reg] + bv1, 0.f) * v2;
            }
        }
        #pragma unroll
        for (int reg = 0; reg < 4; ++reg) {
            vsum[reg] += __shfl_xor(vsum[reg], 1);
            vsum[reg] += __shfl_xor(vsum[reg], 2);
            vsum[reg] += __shfl_xor(vsum[reg], 4);
            vsum[reg] += __shfl_xor(vsum[reg], 8);
        }
        if (mm == 0) {
            #pragma unroll
            for (int reg = 0; reg < 4; ++reg)
                out[b0w + q * 4 + reg] = vsum[reg] + V2_b[0];
        }
    }
}

// ---------------------------------------------------------------------------
// K2a: barrier-free streaming GEMM  W2 = fragment-major bf16 w1_state
// (fix + bias fused). Swapped MFMA orientation: C[M=col][N=row], so each
// lane holds (4 cols x 1 row) -> cvtpk packs the d'-interleaved pair
// (d, d+16) -> one 16B store per E directly in the A-frag layout the
// contraction needs. No LDS, no barriers, pure streaming.
// Wave = E-pair (64 cols) x 64 rows; grid 1024 x 256.
// ---------------------------------------------------------------------------
__global__ __launch_bounds__(256) void k2a_gemm(
    const unsigned short* __restrict__ w1sTf,   // [256][2048] frag-major
    const unsigned short* __restrict__ Sbf,     // [4096][128] bf16 frags
    const float* __restrict__ uncertainty,      // [4096]
    const float* __restrict__ w1s_W,            // row 128 used
    const float* __restrict__ w1s_b,
    unsigned short* __restrict__ W2)            // [4096 r][4096 c'] bf16
{
    const int bx = blockIdx.x;
    const int rb = bx >> 4, pg = bx & 15;       // rb: 64 row-blocks of 64
    const int wave = threadIdx.x >> 6, lane = threadIdx.x & 63;
    const int m = lane & 15, quad = lane >> 4;
    const int ep = pg * 4 + wave;               // E-pair index [0,64)
    const int ct0 = ep * 4;                     // 4 col-tiles = 64 cols

    const float* w128 = w1s_W + (size_t)128 * 4096;

    // A-frags: 4 tiles x 4 ks (w1sTf as A operand; layouts are symmetric)
    short8 A[4][4];
    #pragma unroll
    for (int t = 0; t < 4; ++t)
        #pragma unroll
        for (int ks = 0; ks < 4; ++ks)
            A[t][ks] = *(const short8*)&w1sTf[(size_t)(ct0 + t) * 2048 + ks * 512 + lane * 8];

    // per-tile fix/bias for cols c = (ct0+t)*16 + quad*4 + reg
    float wf[4][4], bb[4][4];
    #pragma unroll
    for (int t = 0; t < 4; ++t) {
        float4 w4 = *(const float4*)&w128[(ct0 + t) * 16 + quad * 4];
        float4 b4 = *(const float4*)&w1s_b[(ct0 + t) * 16 + quad * 4];
        wf[t][0] = w4.x; wf[t][1] = w4.y; wf[t][2] = w4.z; wf[t][3] = w4.w;
        bb[t][0] = b4.x; bb[t][1] = b4.y; bb[t][2] = b4.z; bb[t][3] = b4.w;
    }

    #pragma unroll
    for (int c = 0; c < 4; ++c) {
        const int r0c = rb * 64 + c * 16;
        const float us = uncertainty[r0c + m];   // lane's row = m
        short8 Bf[4];
        #pragma unroll
        for (int ks = 0; ks < 4; ++ks)
            Bf[ks] = *(const short8*)&Sbf[(size_t)(r0c + m) * 128 + ks * 32 + quad * 8];

        float4v z[4];
        #pragma unroll
        for (int t = 0; t < 4; ++t) z[t] = (float4v){0.f, 0.f, 0.f, 0.f};
        #pragma unroll
        for (int t = 0; t < 4; ++t)
            #pragma unroll
            for (int ks = 0; ks < 4; ++ks)
                z[t] = __builtin_amdgcn_mfma_f32_16x16x32_bf16(A[t][ks], Bf[ks], z[t], 0, 0, 0);

        // tiles (0,1) -> E0 = 2*ep (d<16 / d>=16); tiles (2,3) -> E1
        #pragma unroll
        for (int half = 0; half < 2; ++half) {
            const int tA = half * 2, tB = half * 2 + 1;
            unsigned int wpk[4];
            #pragma unroll
            for (int reg = 0; reg < 4; ++reg) {
                float za = z[tA][reg] + us * wf[tA][reg] + bb[tA][reg];
                float zb = z[tB][reg] + us * wf[tB][reg] + bb[tB][reg];
                wpk[reg] = cvtpk(za, zb);        // d' = (2d, 2d+1)
            }
            short8 pk;
            __builtin_memcpy(&pk, wpk, 16);
            const int E = ep * 2 + half;         // [0,128)
            const int eo = (E >> 4) * 512 + (E & 15) * 32 + quad * 8;
            *(short8*)&W2[(size_t)(r0c + m) * 4096 + eo] = pk;
        }
    }
}

// ---------------------------------------------------------------------------
// K1': GAT + contraction + epilogue fused, 1 wave = 1 batch row.
// After the PV MFMA each lane already holds its contraction B-frag octet
// (d' = 8*quad + 2t + p) in registers -> no g round-trip. W2 A-frags
// prefetched at wave start hide under the GAT MFMA chain.
// ---------------------------------------------------------------------------
__global__ __launch_bounds__(256) void k1_gatmix(
    const float* __restrict__ hidden_states,  // [4096*16][64] fp32
    const unsigned short* __restrict__ WgTf,  // [9][1024] bf16 frag-major
    const unsigned short* __restrict__ W2,    // [4096][4096] bf16 frag-major
    const float* __restrict__ agent_qs,       // [4096][16]
    const float* __restrict__ b1v, const float* __restrict__ wfv,
    float* __restrict__ out)                  // seeded with v
{
    const int wave = threadIdx.x >> 6;
    const int b = blockIdx.x * 4 + wave;
    const int lane = threadIdx.x & 63, m = lane & 15, quad = lane >> 4;
    __shared__ __align__(16) float sc[4 * 320];   // per-wave scratch, 5KB
    float* scr = &sc[wave * 320];

    // prefetch W2 A-frags (i = h*2+H), hidden under GAT compute
    short8 wfr[8];
    #pragma unroll
    for (int i = 0; i < 8; ++i)
        wfr[i] = *(const short8*)&W2[(size_t)b * 4096 + i * 512 + m * 32 + quad * 8];
    const float qs_m = agent_qs[b * 16 + m];

    // ---- MFMA1: 8 hp tiles + proj tile ----
    const float* hrow = hidden_states + ((size_t)b * 16 + m) * 64;
    float4 f0 = *(const float4*)(hrow + quad * 8);
    float4 f1 = *(const float4*)(hrow + quad * 8 + 4);
    short8 a0 = pack8(f0, f1);
    f0 = *(const float4*)(hrow + 32 + quad * 8);
    f1 = *(const float4*)(hrow + 32 + quad * 8 + 4);
    short8 a1 = pack8(f0, f1);

    float4v hpt[9];
    #pragma unroll
    for (int nt = 0; nt < 9; ++nt) {
        short8 bf0 = *(const short8*)&WgTf[nt * 1024 + lane * 8];
        short8 bf1 = *(const short8*)&WgTf[nt * 1024 + 512 + lane * 8];
        float4v z = (float4v){0.f, 0.f, 0.f, 0.f};
        z = __builtin_amdgcn_mfma_f32_16x16x32_bf16(a0, bf0, z, 0, 0, 0);
        z = __builtin_amdgcn_mfma_f32_16x16x32_bf16(a1, bf1, z, 0, 0, 0);
        hpt[nt] = z;
    }

    // stash proj tile transposed: scr[col*20 + row]
    {
        float4 pr = {hpt[8][0], hpt[8][1], hpt[8][2], hpt[8][3]};
        *(float4*)&scr[m * 20 + quad * 4] = pr;
    }

    float Sacc[2][4] = {};

    // ---- per head: softmax + PV MFMA + in-register contraction ----
    #pragma unroll
    for (int h = 0; h < 4; ++h) {
        const float src_m = scr[h * 20 + m];                        // src[i=m]
        float4 pdv = *(const float4*)&scr[(4 + h) * 20 + quad * 4]; // dst[j]
        float pd[4] = {pdv.x, pdv.y, pdv.z, pdv.w};

        float e_[4];
        #pragma unroll
        for (int jj = 0; jj < 4; ++jj) {
            float x = src_m + pd[jj];
            e_[jj] = fmaxf(x, 0.2f * x);       // leaky_relu(0.2)
        }
        float mx = fmaxf(fmaxf(e_[0], e_[1]), fmaxf(e_[2], e_[3]));
        mx = fmaxf(mx, __shfl_xor(mx, 16));
        mx = fmaxf(mx, __shfl_xor(mx, 32));
        float p_[4], ssum = 0.f;
        #pragma unroll
        for (int jj = 0; jj < 4; ++jj) { p_[jj] = __expf(e_[jj] - mx); ssum += p_[jj]; }
        ssum += __shfl_xor(ssum, 16);
        ssum += __shfl_xor(ssum, 32);
        const float inv = __builtin_amdgcn_rcpf(ssum);

        half4v bfrag;   // B[k=j=quad*4+jj][n=i=m] = attn[i][j]
        #pragma unroll
        for (int jj = 0; jj < 4; ++jj) bfrag[jj] = (_Float16)(p_[jj] * inv);

        float4v zp[2];
        #pragma unroll
        for (int p = 0; p < 2; ++p) {
            float4v ct = hpt[2 * h + p];       // A[m=d'][k=j=quad*4+t]
            half4v afrag;
            #pragma unroll
            for (int t = 0; t < 4; ++t) afrag[t] = (_Float16)ct[t];
            float4v z = (float4v){0.f, 0.f, 0.f, 0.f};
            zp[p] = __builtin_amdgcn_mfma_f32_16x16x16f16(afrag, bfrag, z, 0, 0, 0);
        }
        // elu + pack: lane's g octet (d' = 8*quad + 2t + p), no store needed
        unsigned int w[4];
        #pragma unroll
        for (int t = 0; t < 4; ++t) {
            float x0 = zp[0][t];
            x0 = (x0 > 0.f) ? x0 : (__expf(x0) - 1.f);
            float x1 = zp[1][t];
            x1 = (x1 > 0.f) ? x1 : (__expf(x1) - 1.f);
            w[t] = cvtpk(x0, x1);
        }
        short8 gfrag;
        __builtin_memcpy(&gfrag, w, 16);

        // contraction: C[M=el][N=agent] = sum_d' W2[el][d'] * g[d'][agent]
        #pragma unroll
        for (int H = 0; H < 2; ++H) {
            float4v z = (float4v){0.f, 0.f, 0.f, 0.f};
            z = __builtin_amdgcn_mfma_f32_16x16x32_bf16(wfr[h * 2 + H], gfrag, z, 0, 0, 0);
            #pragma unroll
            for (int reg = 0; reg < 4; ++reg)
                Sacc[H][reg] += fabsf(z[reg]);
        }
    }

    // ---- epilogue: qs, n-reduce, b1+elu+wf, e-sum, single write ----
    float local = 0.f;
    #pragma unroll
    for (int H = 0; H < 2; ++H) {
        float sn[4];
        #pragma unroll
        for (int reg = 0; reg < 4; ++reg) sn[reg] = Sacc[H][reg] * qs_m;
        #pragma unroll
        for (int mask = 1; mask <= 8; mask <<= 1) {
            #pragma unroll
            for (int reg = 0; reg < 4; ++reg) sn[reg] += __shfl_xor(sn[reg], mask);
        }
        // e = H*16 + quad*4 + reg
        float4 b4 = *(const float4*)&b1v[(size_t)b * 32 + H * 16 + quad * 4];
        float4 w4 = *(const float4*)&wfv[(size_t)b * 32 + H * 16 + quad * 4];
        float bq[4] = {b4.x, b4.y, b4.z, b4.w};
        float wq[4] = {w4.x, w4.y, w4.z, w4.w};
        #pragma unroll
        for (int reg = 0; reg < 4; ++reg) {
            float hid = 0.25f * sn[reg] + bq[reg];
            hid = (hid > 0.f) ? hid : expm1f(hid);
            local = fmaf(hid, wq[reg], local);
        }
    }
    local += __shfl_xor(local, 16);
    local += __shfl_xor(local, 32);
    if (lane == 0) out[b] = out[b] + local;   // seed v already in out
}

// ---------------------------------------------------------------------------
extern "C" void kernel_launch(void* const* d_in, const int* in_sizes, int n_in,
                              void* d_out, int out_size, void* d_ws, size_t ws_size,
                              hipStream_t stream)
{
    const float* agent_qs      = (const float*)d_in[0];
    const float* states        = (const float*)d_in[1];
    const float* hidden_states = (const float*)d_in[2];
    const float* uncertainty   = (const float*)d_in[3];
    const float* W_gat         = (const float*)d_in[4];
    const float* att_a         = (const float*)d_in[5];
    const float* w1s_W         = (const float*)d_in[6];
    const float* w1s_b         = (const float*)d_in[7];
    const float* b1_W          = (const float*)d_in[8];
    const float* b1_b          = (const float*)d_in[9];
    const float* wf_W          = (const float*)d_in[10];
    const float* wf_b          = (const float*)d_in[11];
    const float* V1_W          = (const float*)d_in[12];
    const float* V1_b          = (const float*)d_in[13];
    const float* V2_W          = (const float*)d_in[14];
    const float* V2_b          = (const float*)d_in[15];

    char* w = (char*)d_ws;
    unsigned short* w1sTf   = (unsigned short*)w;  w += (size_t)524288 * 2;
    unsigned short* WgTf    = (unsigned short*)w;  w += (size_t)9216 * 2;
    unsigned short* Sbf     = (unsigned short*)w;  w += (size_t)524288 * 2;
    unsigned short* W2      = (unsigned short*)w;  w += (size_t)16777216 * 2;
    float* b1v              = (float*)w;           w += (size_t)131072 * 4;
    float* wfv              = (float*)w;           w += (size_t)131072 * 4;
    float* out              = (float*)d_out;

    k0_prep<<<321, 256, 0, stream>>>(w1s_W, W_gat, att_a, states,
                                     b1_W, b1_b, wf_W, wf_b, V1_W, V1_b,
                                     V2_W, V2_b, w1sTf, WgTf, Sbf, b1v, wfv, out);

    k2a_gemm<<<1024, 256, 0, stream>>>(w1sTf, Sbf, uncertainty, w1s_W, w1s_b, W2);

    k1_gatmix<<<1024, 256, 0, stream>>>(hidden_states, WgTf, W2, agent_qs,
                                        b1v, wfv, out);
}